// Round 20
// baseline (22.176 us; speedup 1.0000x reference)
//
#include <hip/hip_runtime.h>

// SelfAttention: x[4,4096,64] f32; Wq,Wk[64,16]; Wv[64,64]; out[4,4096,64] f32.
// R20 = R19 + low-risk polish (structural levers exhausted per R12/15/17
//   post-mortems; attn sits at ~50% L2 efficiency with 165MB traffic, the
//   rest of the budget is fixed launch overhead ~8us + gap ~2.5us).
//   1) proj: 32-row blocks (512 thr, grid 512) -> 2 blocks/CU, all CUs busy
//      (was 256 blocks = half the CUs idle at 1 block/CU).
//   2) attn merge: linv[q] computed once by 32 threads (was 32x redundant);
//      normalization multiply moved to the coalesced-store phase.
// Core (unchanged from R19): bf16 MFMA proj with exact hi/lo split, q
//   pre-scaled 1/sqrt(16)*log2e, V in MFMA fragment order; no-max exp2
//   flash attn, pair-balanced blocks (129 32-key tiles), register-dieted
//   do_tile32 (staggered V loads, VALU lsum), packed-bf16 one-pass merge.

#define TSEQ 4096
#define NBATCH 4

typedef __attribute__((ext_vector_type(4)))  float fvec4;
typedef __attribute__((ext_vector_type(16))) float f32x16;
typedef __attribute__((ext_vector_type(4)))  short s16x4;
typedef __attribute__((ext_vector_type(8)))  short s16x8;

union I4S8 { int i[4]; s16x8 v; };

static __device__ __forceinline__ unsigned short f2bf(float f) {
    unsigned u = __float_as_uint(f);
    u += 0x7FFFu + ((u >> 16) & 1u);   // RNE
    return (unsigned short)(u >> 16);
}

static __device__ __forceinline__ int cvt_pk_bf16(float lo, float hi) {
    int r;
    asm("v_cvt_pk_bf16_f32 %0, %1, %2" : "=v"(r) : "v"(lo), "v"(hi));
    return r;
}

static __device__ __forceinline__ s16x8 cat4(s16x4 a, s16x4 b) {
    return __builtin_shufflevector(a, b, 0, 1, 2, 3, 4, 5, 6, 7);
}

// ---------------------------------------------------------------------------
// Projection. 512 thr (8 waves) x 32 x-rows; grid 512 -> 2 blocks/CU.
// Waves 0-2 each run one nt-chain (q/k, v-lo, v-hi) for the 32 rows.
// Block handles key-half (bid&1) of 64-key V tile (bid>>1):
// fragment chunk c = 2*(bid&1) + ci.
// ---------------------------------------------------------------------------
__global__ __launch_bounds__(512)
__attribute__((amdgpu_waves_per_eu(4, 4)))
void proj_kernel(
    const float* __restrict__ x,  const float* __restrict__ Wq,
    const float* __restrict__ Wk, const float* __restrict__ Wv,
    unsigned short* __restrict__ qb, unsigned short* __restrict__ kb,
    unsigned short* __restrict__ vf)
{
    __shared__ float xs[32][66];
    __shared__ __align__(16) unsigned short Wh[96][76], Wl[96][76];

    const int bid  = blockIdx.x;
    const int tid  = threadIdx.x;
    const int w    = tid >> 6;
    const int lane = tid & 63;
    const int col  = lane & 31;
    const int g    = lane >> 5;

    // -- x stage: 32 rows x 64 f32 = 512 float4s, one per thread
    {
        const float* xblk = x + (size_t)bid * 32 * 64;
        const int fi = tid * 4;
        fvec4 v = *(const fvec4*)(xblk + fi);
        const int r = fi >> 6, c = fi & 63;
        xs[r][c + 0] = v[0]; xs[r][c + 1] = v[1];
        xs[r][c + 2] = v[2]; xs[r][c + 3] = v[3];
    }
    const float SCQ = 0.25f * 1.44269504088896340736f; // 1/sqrt(16)*log2(e)
    #pragma unroll
    for (int j = 0; j < 2; ++j) {                      // Wq: 2 values/thread
        const int idx = tid + 512 * j;
        const int n = idx & 15, k = idx >> 4;
        float wv = Wq[idx] * SCQ;
        unsigned short h = f2bf(wv);
        Wh[n][k] = h;
        Wl[n][k] = f2bf(wv - __uint_as_float((unsigned)h << 16));
    }
    #pragma unroll
    for (int j = 0; j < 2; ++j) {                      // Wk: 2 values/thread
        const int idx = tid + 512 * j;
        const int n = idx & 15, k = idx >> 4;
        float wv = Wk[idx];
        unsigned short h = f2bf(wv);
        Wh[16 + n][k] = h;
        Wl[16 + n][k] = f2bf(wv - __uint_as_float((unsigned)h << 16));
    }
    #pragma unroll
    for (int j = 0; j < 8; ++j) {                      // Wv: 8 values/thread
        const int idx = tid + 512 * j;
        const int n = idx & 63, k = idx >> 6;
        float wv = Wv[idx];
        unsigned short h = f2bf(wv);
        Wh[32 + n][k] = h;
        Wl[32 + n][k] = f2bf(wv - __uint_as_float((unsigned)h << 16));
    }
    __syncthreads();

    if (w < 3) {
        const int nt = w;                 // 0: q/k, 1: v lo, 2: v hi
        const int row0 = bid * 32;

        s16x8 xh[4], xl[4];
        #pragma unroll
        for (int kc = 0; kc < 4; ++kc) {
            const float* xp = &xs[col][kc * 16 + 8 * g];
            float2 a0 = *(const float2*)(xp + 0);
            float2 a1 = *(const float2*)(xp + 2);
            float2 a2 = *(const float2*)(xp + 4);
            float2 a3 = *(const float2*)(xp + 6);
            I4S8 uh, ul;
            uh.i[0] = cvt_pk_bf16(a0.x, a0.y);
            uh.i[1] = cvt_pk_bf16(a1.x, a1.y);
            uh.i[2] = cvt_pk_bf16(a2.x, a2.y);
            uh.i[3] = cvt_pk_bf16(a3.x, a3.y);
            ul.i[0] = cvt_pk_bf16(a0.x - __uint_as_float((unsigned)uh.i[0] << 16),
                                  a0.y - __uint_as_float((unsigned)uh.i[0] & 0xffff0000u));
            ul.i[1] = cvt_pk_bf16(a1.x - __uint_as_float((unsigned)uh.i[1] << 16),
                                  a1.y - __uint_as_float((unsigned)uh.i[1] & 0xffff0000u));
            ul.i[2] = cvt_pk_bf16(a2.x - __uint_as_float((unsigned)uh.i[2] << 16),
                                  a2.y - __uint_as_float((unsigned)uh.i[2] & 0xffff0000u));
            ul.i[3] = cvt_pk_bf16(a3.x - __uint_as_float((unsigned)uh.i[3] << 16),
                                  a3.y - __uint_as_float((unsigned)uh.i[3] & 0xffff0000u));
            xh[kc] = uh.v; xl[kc] = ul.v;
        }

        f32x16 acc = (f32x16)0.0f;
        const int n = nt * 32 + col;
        #pragma unroll
        for (int kc = 0; kc < 4; ++kc) {
            const int off = kc * 16 + 8 * g;
            s16x8 bh = cat4(*(const s16x4*)&Wh[n][off], *(const s16x4*)&Wh[n][off + 4]);
            s16x8 bl = cat4(*(const s16x4*)&Wl[n][off], *(const s16x4*)&Wl[n][off + 4]);
            acc = __builtin_amdgcn_mfma_f32_32x32x16_bf16(xh[kc], bh, acc, 0, 0, 0);
            acc = __builtin_amdgcn_mfma_f32_32x32x16_bf16(xl[kc], bh, acc, 0, 0, 0);
            acc = __builtin_amdgcn_mfma_f32_32x32x16_bf16(xh[kc], bl, acc, 0, 0, 0);
        }

        if (nt == 0) {
            unsigned short* dst = (col < 16) ? (qb + col) : (kb + (col - 16));
            #pragma unroll
            for (int rr = 0; rr < 16; ++rr) {
                const int grow = row0 + (rr & 3) + 8 * (rr >> 2) + 4 * g;
                dst[(size_t)grow * 16] = f2bf(acc[rr]);
            }
        } else {
            const int mt = nt - 1;
            const int hf = bid & 1;                    // key-half of the tile
            unsigned short* const vtile = vf + (size_t)(bid >> 1) * 4096;
            #pragma unroll
            for (int ci = 0; ci < 2; ++ci) {
                I4S8 pk;
                pk.i[0] = cvt_pk_bf16(acc[8*ci + 0], acc[8*ci + 1]);
                pk.i[1] = cvt_pk_bf16(acc[8*ci + 2], acc[8*ci + 3]);
                pk.i[2] = cvt_pk_bf16(acc[8*ci + 4], acc[8*ci + 5]);
                pk.i[3] = cvt_pk_bf16(acc[8*ci + 6], acc[8*ci + 7]);
                const int c = 2 * hf + ci;
                *(s16x8*)(vtile + ((c * 2 + mt) * 64 + lane) * 8) = pk.v;
            }
        }
    }
}

// ---------------------------------------------------------------------------
// One 32-key tile (R19). DIAG: triangular mask. Staggered V loads, VALU lsum.
// ---------------------------------------------------------------------------
template<bool DIAG>
static __device__ __forceinline__ void do_tile32(
    const unsigned short* kp, const unsigned short* vt, const int lane,
    const s16x8 qf, const int col, const int g,
    f32x16& o0, f32x16& o1, float& lsum)
{
    s16x8 kf   = *(const s16x8*)(kp);
    s16x8 va00 = *(const s16x8*)(vt + (0 * 64 + lane) * 8);
    s16x8 va01 = *(const s16x8*)(vt + (1 * 64 + lane) * 8);

    f32x16 s = __builtin_amdgcn_mfma_f32_32x32x16_bf16(kf, qf, (f32x16)0.0f, 0, 0, 0);

    s16x8 va10 = *(const s16x8*)(vt + (2 * 64 + lane) * 8);
    s16x8 va11 = *(const s16x8*)(vt + (3 * 64 + lane) * 8);

    float psA = 0.f, psB = 0.f, psC = 0.f, psD = 0.f;
    #pragma unroll
    for (int rr = 0; rr < 16; ++rr) {
        float ev = __builtin_amdgcn_exp2f(s[rr]);
        if (DIAG) {
            const int drow = (rr & 3) + 8 * (rr >> 2) + 4 * g;
            ev = (drow <= col) ? ev : 0.f;
        }
        s[rr] = ev;
        if ((rr & 3) == 0) psA += ev; else if ((rr & 3) == 1) psB += ev;
        else if ((rr & 3) == 2) psC += ev; else psD += ev;
    }
    lsum += (psA + psB) + (psC + psD);

    I4S8 pa, pb;
    pa.i[0] = cvt_pk_bf16(s[0],  s[1]);
    pa.i[1] = cvt_pk_bf16(s[2],  s[3]);
    pa.i[2] = cvt_pk_bf16(s[4],  s[5]);
    pa.i[3] = cvt_pk_bf16(s[6],  s[7]);
    pb.i[0] = cvt_pk_bf16(s[8],  s[9]);
    pb.i[1] = cvt_pk_bf16(s[10], s[11]);
    pb.i[2] = cvt_pk_bf16(s[12], s[13]);
    pb.i[3] = cvt_pk_bf16(s[14], s[15]);

    o0 = __builtin_amdgcn_mfma_f32_32x32x16_bf16(va00, pa.v, o0, 0, 0, 0);
    o1 = __builtin_amdgcn_mfma_f32_32x32x16_bf16(va01, pa.v, o1, 0, 0, 0);
    o0 = __builtin_amdgcn_mfma_f32_32x32x16_bf16(va10, pb.v, o0, 0, 0, 0);
    o1 = __builtin_amdgcn_mfma_f32_32x32x16_bf16(va11, pb.v, o1, 0, 0, 0);
}

// ---------------------------------------------------------------------------
// Flash attention. 1024 thr = 16 waves; grid (64, NBATCH). Block p does
// q-tiles p and 127-p: 129 32-key tiles. Wave w: t = w, w+16, ... with
// incremental pointers. Packed-bf16 one-pass merge; linv computed once per
// q-row (32 threads), normalization applied at the coalesced store.
// ---------------------------------------------------------------------------
__global__ __launch_bounds__(1024)
__attribute__((amdgpu_waves_per_eu(4, 4)))
void attn_kernel(
    const unsigned short* __restrict__ qb, const unsigned short* __restrict__ kb,
    const unsigned short* __restrict__ vf, float* __restrict__ out)
{
    __shared__ float pl[16][32];
    __shared__ float linv[32];
    __shared__ int   pOi[1024 * 17];     // [dvp*32+q]*17 + w; packed bf16 pairs
    __shared__ float outS[32][66];       // store bounce (coalescing)

    const int tid  = threadIdx.x;
    const int w    = tid >> 6;
    const int lane = tid & 63;
    const int col  = lane & 31;
    const int g    = lane >> 5;
    const int b    = blockIdx.y;
    const int p    = blockIdx.x;

    const unsigned short* const kbase = kb + (size_t)b * TSEQ * 16 + (size_t)col * 16 + 8 * g;
    const unsigned short* const vbase = vf + (size_t)b * 64 * 4096
                                      + (size_t)(w >> 1) * 4096 + (w & 1) * 2048;

    for (int half = 0; half < 2; ++half) {
        const int i  = half ? (127 - p) : p;
        const int q0 = i * 32;

        const s16x8 qf = *(const s16x8*)(qb + ((size_t)(b * TSEQ) + q0 + col) * 16 + 8 * g);

        f32x16 o0 = (f32x16)0.0f, o1 = (f32x16)0.0f;
        float lsum = 0.f;

        // incremental tile pointers: t = w + 16k -> kp += 16*512, vt += 8*4096
        const unsigned short* kp = kbase + (size_t)w * 512;
        const unsigned short* vt = vbase;
        int t = w;
        for (; t < i; t += 16) {             // full 32-key tiles
            do_tile32<false>(kp, vt, lane, qf, col, g, o0, o1, lsum);
            kp += 8192; vt += 32768;
        }
        if (t == i) {                        // this wave owns the diagonal tile
            do_tile32<true>(kp, vt, lane, qf, col, g, o0, o1, lsum);
        }
        lsum += __shfl_xor(lsum, 32);

        // -- write partials: lsum f32; O as packed bf16 dv-pairs (d0 even)
        if (g == 0) pl[w][col] = lsum;
        #pragma unroll
        for (int mt = 0; mt < 2; ++mt) {
            const f32x16 oa = mt ? o1 : o0;
            #pragma unroll
            for (int j = 0; j < 8; ++j) {
                const int rr = 2 * j;
                const int d0 = mt * 32 + (rr & 3) + 8 * (rr >> 2) + 4 * g;
                pOi[((d0 >> 1) * 32 + col) * 17 + w] = cvt_pk_bf16(oa[rr], oa[rr + 1]);
            }
        }
        __syncthreads();

        // -- linv once per q-row (32 threads); raw sums by all threads
        if (tid < 32) {
            float L = 0.f;
            #pragma unroll
            for (int ww = 0; ww < 16; ++ww) L += pl[ww][tid];
            linv[tid] = 1.0f / L;
        }
        {
            const int q   = tid & 31;
            const int dvp = tid >> 5;        // dv pair index 0..31
            const int* prow = &pOi[(dvp * 32 + q) * 17];
            float sA = 0.f, sB = 0.f;
            #pragma unroll
            for (int c = 0; c < 16; ++c) {
                const int v = prow[c];
                sA += __uint_as_float((unsigned)v << 16);
                sB += __uint_as_float((unsigned)v & 0xffff0000u);
            }
            outS[q][2 * dvp + 0] = sA;
            outS[q][2 * dvp + 1] = sB;
        }
        __syncthreads();

        // -- coalesced store with normalization: thread (q2, dvq)
        {
            const int q2  = tid >> 5;
            const int dvq = (tid & 31) * 2;
            float2 v2 = *(const float2*)&outS[q2][dvq];
            const float iv = linv[q2];
            v2.x *= iv; v2.y *= iv;
            *(float2*)(out + ((size_t)(b * TSEQ) + q0 + q2) * 64 + dvq) = v2;
        }
        // LDS reuse in next half is safe: reads completed before the barrier.
    }
}

// ---------------------------------------------------------------------------
extern "C" void kernel_launch(void* const* d_in, const int* in_sizes, int n_in,
                              void* d_out, int out_size, void* d_ws, size_t ws_size,
                              hipStream_t stream) {
    const float* x  = (const float*)d_in[0];
    const float* Wq = (const float*)d_in[1];
    const float* Wk = (const float*)d_in[2];
    const float* Wv = (const float*)d_in[3];

    // workspace: q (512KiB) | k (512KiB) | v-fragments (2MiB) = 3 MiB
    unsigned short* qb = (unsigned short*)d_ws;
    unsigned short* kb = qb + (size_t)NBATCH * TSEQ * 16;
    unsigned short* vf = kb + (size_t)NBATCH * TSEQ * 16;
    float* out = (float*)d_out;

    proj_kernel<<<dim3((NBATCH * TSEQ) / 32), 512, 0, stream>>>(x, Wq, Wk, Wv, qb, kb, vf);
    attn_kernel<<<dim3(64, NBATCH), 1024, 0, stream>>>(qb, kb, vf, out);
}